// Round 1
// baseline (6621.613 us; speedup 1.0000x reference)
//
#include <hip/hip_runtime.h>
#include <cmath>

// ---------------- problem constants ----------------
constexpr int N = 20000, T = 13, E = 320000;
constexpr int CCH = 32;           // C_RES == C_DIL
constexpr int CSKIP = 256, CEND = 512, OUTC = 24;

// ---------------- workspace layout ----------------
constexpr size_t WALIGN = 512;
constexpr size_t align_up(size_t x) { return (x + WALIGN - 1) & ~(WALIGN - 1); }

constexpr size_t XA_OFF  = 0;
constexpr size_t X_SZ    = align_up((size_t)N * 13 * 32 * 4);
constexpr size_t XB_OFF  = XA_OFF + X_SZ;
constexpr size_t H_OFF   = XB_OFF + X_SZ;
constexpr size_t H_SZ    = align_up((size_t)N * 12 * 32 * 4);
constexpr size_t C1_OFF  = H_OFF + H_SZ;
constexpr size_t C2_OFF  = C1_OFF + H_SZ;
constexpr size_t C3_OFF  = C2_OFF + H_SZ;
constexpr size_t HL_OFF  = C3_OFF + H_SZ;
constexpr size_t HL_SZ   = align_up((size_t)N * 256 * 4);
constexpr size_t WS2_OFF = HL_OFF + HL_SZ;                 // skip_w transposed 256x256
constexpr size_t SB_OFF  = WS2_OFF + align_up(256 * 256 * 4);
constexpr size_t SUMS_OFF = SB_OFF + align_up(256 * 4);    // 8 layers x 64 floats
constexpr size_t PAR_OFF  = SUMS_OFF + align_up(8 * 64 * 4); // 9 slots x 64 floats
constexpr size_t CNT_OFF  = PAR_OFF + align_up(9 * 64 * 4);
constexpr size_t ROW_OFF  = CNT_OFF + align_up((size_t)N * 4);
constexpr size_t FILL_OFF = ROW_OFF + align_up((size_t)(N + 1) * 4);
constexpr size_t COL_OFF  = FILL_OFF + align_up((size_t)N * 4);
constexpr size_t DEG_OFF  = COL_OFF + align_up((size_t)E * 4);
// aliases used after all layers are done:
constexpr size_t S_OFF  = C2_OFF;   // N*256 floats  (fits: 20.5MB <= 30.7MB)
constexpr size_t Y1_OFF = H_OFF;    // N*512 floats  (spans H+C1: 41MB <= 61.4MB, no overlap with S)

// ---------------- CSR build ----------------
__global__ void k_count(const int* __restrict__ dst, int* __restrict__ cnt) {
  int i = blockIdx.x * 256 + threadIdx.x;
  if (i < E) atomicAdd(&cnt[dst[i]], 1);
}

__global__ __launch_bounds__(256) void k_scan(const int* __restrict__ cnt, int* __restrict__ rowptr,
                                              int* __restrict__ fill, float* __restrict__ deginv) {
  __shared__ int sc[256];
  int tid = threadIdx.x;
  constexpr int CH = (N + 255) / 256;
  int start = tid * CH;
  int s = 0;
  for (int i = 0; i < CH; i++) { int idx = start + i; if (idx < N) s += cnt[idx]; }
  sc[tid] = s; __syncthreads();
  for (int off = 1; off < 256; off <<= 1) {
    int v = (tid >= off) ? sc[tid - off] : 0;
    __syncthreads();
    sc[tid] += v;
    __syncthreads();
  }
  int run = (tid == 0) ? 0 : sc[tid - 1];
  for (int i = 0; i < CH; i++) {
    int idx = start + i;
    if (idx < N) {
      int v = cnt[idx];
      rowptr[idx] = run; fill[idx] = run;
      deginv[idx] = 1.0f / (float)(v > 1 ? v : 1);
      run += v;
    }
  }
  if (tid == 255) rowptr[N] = run;
}

__global__ void k_scatter(const int* __restrict__ src, const int* __restrict__ dst,
                          int* __restrict__ fill, int* __restrict__ col) {
  int i = blockIdx.x * 256 + threadIdx.x;
  if (i < E) { int d = dst[i]; int p = atomicAdd(&fill[d], 1); col[p] = src[i]; }
}

__global__ void k_init_params(float* __restrict__ par) {
  int i = threadIdx.x;                 // 64 threads: slot 0 = identity affine
  par[i] = (i < 32) ? 1.0f : 0.0f;
}

// ---------------- enter 1x1 conv: inputs [N,T,3] -> x [n][t][c] ----------------
__global__ void k_enter(const float* __restrict__ in, const float* __restrict__ w,
                        const float* __restrict__ b, float* __restrict__ x) {
  int idx = blockIdx.x * 256 + threadIdx.x;
  if (idx >= N * 13 * 32) return;
  int c = idx & 31; int tmp = idx >> 5; int t = tmp % 13; int n = tmp / 13;
  const float* ip = in + (size_t)n * (13 * 3) + t * 3;
  x[idx] = b[c] + w[c * 3 + 0] * ip[0] + w[c * 3 + 1] * ip[1] + w[c * 3 + 2] * ip[2];
}

// ---------------- gated dilated conv (+ hlast capture) ----------------
// x layout [n][t][32] (pre-norm); affine (scale,shift) of slot applied on load.
template <int TIN, int TOUT, int D>
__global__ __launch_bounds__(256) void k_conv(const float* __restrict__ x,
    const float* __restrict__ fw, const float* __restrict__ fb,
    const float* __restrict__ gw, const float* __restrict__ gb,
    const float* __restrict__ par, int slot, int layer,
    float* __restrict__ h, float* __restrict__ hlast) {
  __shared__ float wf[64 * 33], wg[64 * 33];      // [2i+k][o] padded stride 33
  __shared__ float xs[8][TIN * 32];
  int tx = threadIdx.x, ty = threadIdx.y;
  int tid = ty * 32 + tx;
  const float* fwl = fw + (size_t)layer * 2048;   // [o][i][k] linear = o*64 + 2i + k
  const float* gwl = gw + (size_t)layer * 2048;
  for (int i = tid; i < 2048; i += 256) {
    int o = i >> 6, r = i & 63;
    wf[r * 33 + o] = fwl[i];
    wg[r * 33 + o] = gwl[i];
  }
  int n0 = blockIdx.x * 8;
  const float* scp = par + slot * 64;
  for (int i = tid; i < 8 * TIN * 32; i += 256) {
    int nl = i / (TIN * 32), j = i % (TIN * 32); int c = j & 31;
    int gn = n0 + nl;
    xs[nl][j] = (gn < N) ? (scp[c] * x[(size_t)gn * (TIN * 32) + j] + scp[32 + c]) : 0.0f;
  }
  __syncthreads();
  int o = tx, nn = ty, n = n0 + nn;
  float accF[TOUT], accG[TOUT];
  float fbv = fb[layer * 32 + o], gbv = gb[layer * 32 + o];
#pragma unroll
  for (int t = 0; t < TOUT; t++) { accF[t] = fbv; accG[t] = gbv; }
#pragma unroll
  for (int i = 0; i < 32; i++) {
    float xv[TIN];
#pragma unroll
    for (int t = 0; t < TIN; t++) xv[t] = xs[nn][t * 32 + i];
    float w0 = wf[(2 * i) * 33 + o], w1 = wf[(2 * i + 1) * 33 + o];
    float g0 = wg[(2 * i) * 33 + o], g1 = wg[(2 * i + 1) * 33 + o];
#pragma unroll
    for (int t = 0; t < TOUT; t++) {
      accF[t] += w0 * xv[t] + w1 * xv[t + D];
      accG[t] += g0 * xv[t] + g1 * xv[t + D];
    }
  }
  if (n < N) {
#pragma unroll
    for (int t = 0; t < TOUT; t++) {
      float hv = tanhf(accF[t]) * (1.0f / (1.0f + __expf(-accG[t])));
      h[(size_t)n * (TOUT * 32) + t * 32 + o] = hv;
      if (t == TOUT - 1) hlast[(size_t)n * 256 + layer * 32 + o] = hv;
    }
  }
}

// ---------------- one diffusion hop: out[n] = (sum_{src in in-edges(n)} in[src]) / deg[n] ----------------
template <int F>
__global__ __launch_bounds__(256) void k_hop(const float* __restrict__ in, float* __restrict__ out,
    const int* __restrict__ rowptr, const int* __restrict__ col, const float* __restrict__ deginv) {
  int wid = (blockIdx.x * 256 + threadIdx.x) >> 6;   // one wave per node
  int lane = threadIdx.x & 63;
  if (wid >= N) return;
  int s = rowptr[wid], e = rowptr[wid + 1];
  constexpr int NCH = (F + 63) / 64;
  float acc[NCH];
#pragma unroll
  for (int k = 0; k < NCH; k++) acc[k] = 0.0f;
  for (int idx = s; idx < e; ++idx) {
    int srcn = col[idx];
    const float* p = in + (size_t)srcn * F;
#pragma unroll
    for (int k = 0; k < NCH; k++) {
      int j = k * 64 + lane;
      if (j < F) acc[k] += p[j];
    }
  }
  float inv = deginv[wid];
  float* q = out + (size_t)wid * F;
#pragma unroll
  for (int k = 0; k < NCH; k++) { int j = k * 64 + lane; if (j < F) q[j] = acc[k] * inv; }
}

// ---------------- combine: acc = sum_k cur_k @ gc_w[k] + gc_b + norm(x_resid); BN partial stats ----------------
template <int TOUT>
__global__ __launch_bounds__(256) void k_combine(const float* __restrict__ h,
    const float* __restrict__ c1, const float* __restrict__ c2, const float* __restrict__ c3,
    const float* __restrict__ gcw, const float* __restrict__ gcb,
    const float* __restrict__ xcur, int tin, int layer,
    const float* __restrict__ par, int slot,
    float* __restrict__ xnext, float* __restrict__ sums) {
  __shared__ float ls[8][TOUT * 32];
  __shared__ float r1[32], r2[32];
  int tx = threadIdx.x, ty = threadIdx.y;
  int tid = ty * 32 + tx;
  int n0 = blockIdx.x * 8; int n = n0 + ty;
  float acc[TOUT];
#pragma unroll
  for (int t = 0; t < TOUT; t++) acc[t] = 0.0f;
  const float* srcs[4] = { h, c1, c2, c3 };
#pragma unroll
  for (int k = 0; k < 4; k++) {
    const float* src = srcs[k];
    __syncthreads();
    for (int i = tid; i < 8 * TOUT * 32; i += 256) {
      int nl = i / (TOUT * 32), j = i % (TOUT * 32);
      int gn = n0 + nl;
      ls[nl][j] = (gn < N) ? src[(size_t)gn * (TOUT * 32) + j] : 0.0f;
    }
    __syncthreads();
    float wreg[32];
    const float* wp = gcw + (size_t)(layer * 4 + k) * 1024 + tx;  // [l][k][c][o]
#pragma unroll
    for (int c = 0; c < 32; c++) wreg[c] = wp[c * 32];
#pragma unroll
    for (int t = 0; t < TOUT; t++) {
#pragma unroll
      for (int c = 0; c < 32; c++) acc[t] += ls[ty][t * 32 + c] * wreg[c];
    }
  }
  float s1 = 0.0f, s2 = 0.0f;
  if (n < N) {
    float gb = gcb[layer * 32 + tx];
    float psc = par[slot * 64 + tx], psh = par[slot * 64 + 32 + tx];
    int toff = tin - TOUT;
#pragma unroll
    for (int t = 0; t < TOUT; t++) {
      float xr = xcur[(size_t)n * (tin * 32) + (toff + t) * 32 + tx];
      float v = acc[t] + gb + psc * xr + psh;
      xnext[(size_t)n * (TOUT * 32) + t * 32 + tx] = v;
      s1 += v; s2 += v * v;
    }
  }
  if (tid < 32) { r1[tid] = 0.0f; r2[tid] = 0.0f; }
  __syncthreads();
  atomicAdd(&r1[tx], s1);
  atomicAdd(&r2[tx], s2);
  __syncthreads();
  if (ty == 0) {
    atomicAdd(&sums[layer * 64 + tx], r1[tx]);
    atomicAdd(&sums[layer * 64 + 32 + tx], r2[tx]);
  }
}

// ---------------- BN stats -> affine params for next slot ----------------
__global__ void k_bnfin(const float* __restrict__ sums, const float* __restrict__ bng,
                        const float* __restrict__ bnb, float* __restrict__ par,
                        int layer, int tout) {
  int o = threadIdx.x;  // 32
  float cnt = (float)N * (float)tout;
  float s1 = sums[layer * 64 + o], s2 = sums[layer * 64 + 32 + o];
  float mu = s1 / cnt;
  float var = s2 / cnt - mu * mu;
  float sc = bng[layer * 32 + o] * rsqrtf(var + 1e-5f);
  par[(layer + 1) * 64 + o] = sc;
  par[(layer + 1) * 64 + 32 + o] = bnb[layer * 32 + o] - mu * sc;
}

// ---------------- head prep ----------------
__global__ void k_prep_skipw(const float* __restrict__ sw, float* __restrict__ w2) {
  int idx = blockIdx.x * 256 + threadIdx.x;
  if (idx >= 8 * 256 * 32) return;
  int l = idx / (256 * 32), r = idx % (256 * 32), o = r / 32, c = r & 31;
  w2[o * 256 + l * 32 + c] = sw[idx];
}
__global__ void k_prep_sb(const float* __restrict__ sb, float* __restrict__ out) {
  int o = threadIdx.x;  // 256
  float s = 0.0f;
  for (int l = 0; l < 8; l++) s += sb[l * 256 + o];
  out[o] = s;
}

// ---------------- generic tiled fp32 GEMM: C[M,O] = act(A[M,K] @ W[O,K]^T + bias) ----------------
__global__ __launch_bounds__(256) void k_gemm(const float* __restrict__ A, const float* __restrict__ W,
    const float* __restrict__ bias, float* __restrict__ Cout,
    int M, int K, int Onum, int relu) {
  __shared__ float As[16][68];
  __shared__ float Wsh[16][68];
  int tid = threadIdx.x;
  int bm = blockIdx.x * 64, bo = blockIdx.y * 64;
  int tm = (tid >> 4) << 2, to = (tid & 15) << 2;
  float acc[4][4] = {};
  int lm = tid >> 2, kq = (tid & 3) << 2;
  for (int k0 = 0; k0 < K; k0 += 16) {
    float4 av = make_float4(0.f, 0.f, 0.f, 0.f);
    int gm = bm + lm;
    if (gm < M) av = *(const float4*)(A + (size_t)gm * K + k0 + kq);
    As[kq + 0][lm] = av.x; As[kq + 1][lm] = av.y; As[kq + 2][lm] = av.z; As[kq + 3][lm] = av.w;
    float4 wv = *(const float4*)(W + (size_t)(bo + lm) * K + k0 + kq);
    Wsh[kq + 0][lm] = wv.x; Wsh[kq + 1][lm] = wv.y; Wsh[kq + 2][lm] = wv.z; Wsh[kq + 3][lm] = wv.w;
    __syncthreads();
#pragma unroll
    for (int k = 0; k < 16; k++) {
      float am[4], wn[4];
#pragma unroll
      for (int j = 0; j < 4; j++) { am[j] = As[k][tm + j]; wn[j] = Wsh[k][to + j]; }
#pragma unroll
      for (int i = 0; i < 4; i++)
#pragma unroll
        for (int j = 0; j < 4; j++) acc[i][j] += am[i] * wn[j];
    }
    __syncthreads();
  }
#pragma unroll
  for (int i = 0; i < 4; i++) {
    int gm = bm + tm + i; if (gm >= M) continue;
#pragma unroll
    for (int j = 0; j < 4; j++) {
      int go = bo + to + j;
      float v = acc[i][j] + bias[go];
      if (relu) v = fmaxf(v, 0.0f);
      Cout[(size_t)gm * Onum + go] = v;
    }
  }
}

// ---------------- final small GEMM -> d_out [N,24] ----------------
__global__ void k_final(const float* __restrict__ Y1, const float* __restrict__ W2,
                        const float* __restrict__ b2, float* __restrict__ out) {
  int idx = blockIdx.x * 256 + threadIdx.x;
  if (idx >= N * 24) return;
  int n = idx / 24, o = idx % 24;
  const float4* a = (const float4*)(Y1 + (size_t)n * 512);
  const float4* w = (const float4*)(W2 + (size_t)o * 512);
  float s = b2[o];
  for (int k = 0; k < 128; k++) {
    float4 av = a[k], wv = w[k];
    s += av.x * wv.x + av.y * wv.y + av.z * wv.z + av.w * wv.w;
  }
  out[idx] = s;
}

// ---------------- host side ----------------
struct Ptrs {
  const float *fw, *fb, *gw, *gb, *gcw, *gcb, *bng, *bnb;
  float *H, *C1, *C2, *C3, *HL, *par, *sums;
  const int *row, *col;
  const float *deg;
};

template <int TIN, int TOUT, int D>
static void run_layer(int layer, bool last, const Ptrs& P, float*& xc, float*& xn, hipStream_t stream) {
  dim3 cb(32, 8);
  int blocks = (N + 7) / 8;
  k_conv<TIN, TOUT, D><<<blocks, cb, 0, stream>>>(xc, P.fw, P.fb, P.gw, P.gb, P.par, layer, layer, P.H, P.HL);
  if (!last) {
    constexpr int F = TOUT * 32;
    int hb = (N * 64 + 255) / 256;
    k_hop<F><<<hb, 256, 0, stream>>>(P.H, P.C1, P.row, P.col, P.deg);
    k_hop<F><<<hb, 256, 0, stream>>>(P.C1, P.C2, P.row, P.col, P.deg);
    k_hop<F><<<hb, 256, 0, stream>>>(P.C2, P.C3, P.row, P.col, P.deg);
    k_combine<TOUT><<<blocks, cb, 0, stream>>>(P.H, P.C1, P.C2, P.C3, P.gcw, P.gcb, xc, TIN, layer,
                                               P.par, layer, xn, P.sums);
    k_bnfin<<<1, 32, 0, stream>>>(P.sums, P.bng, P.bnb, P.par, layer, TOUT);
    float* tmp = xc; xc = xn; xn = tmp;
  }
}

extern "C" void kernel_launch(void* const* d_in, const int* in_sizes, int n_in,
                              void* d_out, int out_size, void* d_ws, size_t ws_size,
                              hipStream_t stream) {
  const float* inputs  = (const float*)d_in[0];
  const int*   esrc    = (const int*)d_in[1];
  const int*   edst    = (const int*)d_in[2];
  const float* enter_w = (const float*)d_in[3];
  const float* enter_b = (const float*)d_in[4];
  const float* filt_w  = (const float*)d_in[5];
  const float* filt_b  = (const float*)d_in[6];
  const float* gate_w  = (const float*)d_in[7];
  const float* gate_b  = (const float*)d_in[8];
  const float* gc_w    = (const float*)d_in[9];
  const float* gc_b    = (const float*)d_in[10];
  const float* skip_w  = (const float*)d_in[11];
  const float* skip_b  = (const float*)d_in[12];
  const float* bn_g    = (const float*)d_in[13];
  const float* bn_b    = (const float*)d_in[14];
  const float* out1_w  = (const float*)d_in[15];
  const float* out1_b  = (const float*)d_in[16];
  const float* out2_w  = (const float*)d_in[17];
  const float* out2_b  = (const float*)d_in[18];

  char* ws = (char*)d_ws;
  float* XA  = (float*)(ws + XA_OFF);
  float* XB  = (float*)(ws + XB_OFF);
  float* H   = (float*)(ws + H_OFF);
  float* C1  = (float*)(ws + C1_OFF);
  float* C2  = (float*)(ws + C2_OFF);
  float* C3  = (float*)(ws + C3_OFF);
  float* HL  = (float*)(ws + HL_OFF);
  float* WS2 = (float*)(ws + WS2_OFF);
  float* SB  = (float*)(ws + SB_OFF);
  float* SUMS = (float*)(ws + SUMS_OFF);
  float* PAR  = (float*)(ws + PAR_OFF);
  int* CNT  = (int*)(ws + CNT_OFF);
  int* ROW  = (int*)(ws + ROW_OFF);
  int* FILL = (int*)(ws + FILL_OFF);
  int* COL  = (int*)(ws + COL_OFF);
  float* DEG = (float*)(ws + DEG_OFF);
  float* S  = (float*)(ws + S_OFF);
  float* Y1 = (float*)(ws + Y1_OFF);

  hipMemsetAsync(CNT, 0, (size_t)N * 4, stream);
  hipMemsetAsync(SUMS, 0, 8 * 64 * 4, stream);

  k_count<<<(E + 255) / 256, 256, 0, stream>>>(edst, CNT);
  k_scan<<<1, 256, 0, stream>>>(CNT, ROW, FILL, DEG);
  k_scatter<<<(E + 255) / 256, 256, 0, stream>>>(esrc, edst, FILL, COL);
  k_init_params<<<1, 64, 0, stream>>>(PAR);
  k_enter<<<(N * 13 * 32 + 255) / 256, 256, 0, stream>>>(inputs, enter_w, enter_b, XA);
  k_prep_skipw<<<(8 * 256 * 32 + 255) / 256, 256, 0, stream>>>(skip_w, WS2);
  k_prep_sb<<<1, 256, 0, stream>>>(skip_b, SB);

  Ptrs P;
  P.fw = filt_w; P.fb = filt_b; P.gw = gate_w; P.gb = gate_b;
  P.gcw = gc_w; P.gcb = gc_b; P.bng = bn_g; P.bnb = bn_b;
  P.H = H; P.C1 = C1; P.C2 = C2; P.C3 = C3; P.HL = HL; P.par = PAR; P.sums = SUMS;
  P.row = ROW; P.col = COL; P.deg = DEG;

  float* xc = XA; float* xn = XB;
  run_layer<13, 12, 1>(0, false, P, xc, xn, stream);
  run_layer<12, 10, 2>(1, false, P, xc, xn, stream);
  run_layer<10, 9, 1>(2, false, P, xc, xn, stream);
  run_layer<9, 7, 2>(3, false, P, xc, xn, stream);
  run_layer<7, 6, 1>(4, false, P, xc, xn, stream);
  run_layer<6, 4, 2>(5, false, P, xc, xn, stream);
  run_layer<4, 3, 1>(6, false, P, xc, xn, stream);
  run_layer<3, 1, 2>(7, true, P, xc, xn, stream);

  // head: S = relu(HL @ WS2^T + SB); Y1 = relu(S @ out1_w^T + out1_b); out = Y1 @ out2_w^T + out2_b
  dim3 g1((N + 63) / 64, 256 / 64);
  k_gemm<<<g1, 256, 0, stream>>>(HL, WS2, SB, S, N, 256, 256, 1);
  dim3 g2((N + 63) / 64, 512 / 64);
  k_gemm<<<g2, 256, 0, stream>>>(S, out1_w, out1_b, Y1, N, 256, 512, 1);
  k_final<<<(N * 24 + 255) / 256, 256, 0, stream>>>(Y1, out2_w, out2_b, (float*)d_out);
}

// Round 2
// 4844.484 us; speedup vs baseline: 1.3668x; 1.3668x over previous
//
#include <hip/hip_runtime.h>
#include <cmath>

// ---------------- problem constants ----------------
constexpr int N = 20000, T = 13, E = 320000;

// ---------------- workspace layout ----------------
constexpr size_t WALIGN = 512;
constexpr size_t align_up(size_t x) { return (x + WALIGN - 1) & ~(WALIGN - 1); }

constexpr size_t XA_OFF  = 0;
constexpr size_t X_SZ    = align_up((size_t)N * 13 * 32 * 4);
constexpr size_t XB_OFF  = XA_OFF + X_SZ;
constexpr size_t H_OFF   = XB_OFF + X_SZ;
constexpr size_t H_SZ    = align_up((size_t)N * 12 * 32 * 4);
constexpr size_t C1_OFF  = H_OFF + H_SZ;
constexpr size_t C2_OFF  = C1_OFF + H_SZ;
constexpr size_t C3_OFF  = C2_OFF + H_SZ;
constexpr size_t HL_OFF  = C3_OFF + H_SZ;
constexpr size_t HL_SZ   = align_up((size_t)N * 256 * 4);
constexpr size_t WS2_OFF = HL_OFF + HL_SZ;                 // skip_w transposed 256x256
constexpr size_t SB_OFF  = WS2_OFF + align_up(256 * 256 * 4);
constexpr size_t SUMS_OFF = SB_OFF + align_up(256 * 4);    // 8 layers x 64 floats
constexpr size_t PAR_OFF  = SUMS_OFF + align_up(8 * 64 * 4); // 9 slots x 64 floats
constexpr size_t CNT_OFF  = PAR_OFF + align_up(9 * 64 * 4);
constexpr size_t ROW_OFF  = CNT_OFF + align_up((size_t)N * 4);
constexpr size_t FILL_OFF = ROW_OFF + align_up((size_t)(N + 1) * 4);
constexpr size_t COL_OFF  = FILL_OFF + align_up((size_t)N * 4);
constexpr size_t DEG_OFF  = COL_OFF + align_up((size_t)E * 4);
// aliases used after all layers are done:
constexpr size_t S_OFF  = C2_OFF;   // N*256 floats
constexpr size_t Y1_OFF = H_OFF;    // N*512 floats (spans H+C1)

// ---------------- CSR build ----------------
__global__ void k_count(const int* __restrict__ dst, int* __restrict__ cnt) {
  int i = blockIdx.x * 256 + threadIdx.x;
  if (i < E) atomicAdd(&cnt[dst[i]], 1);
}

__global__ __launch_bounds__(256) void k_scan(const int* __restrict__ cnt, int* __restrict__ rowptr,
                                              int* __restrict__ fill, float* __restrict__ deginv) {
  __shared__ int sc[256];
  int tid = threadIdx.x;
  constexpr int CH = (N + 255) / 256;
  int start = tid * CH;
  int s = 0;
  for (int i = 0; i < CH; i++) { int idx = start + i; if (idx < N) s += cnt[idx]; }
  sc[tid] = s; __syncthreads();
  for (int off = 1; off < 256; off <<= 1) {
    int v = (tid >= off) ? sc[tid - off] : 0;
    __syncthreads();
    sc[tid] += v;
    __syncthreads();
  }
  int run = (tid == 0) ? 0 : sc[tid - 1];
  for (int i = 0; i < CH; i++) {
    int idx = start + i;
    if (idx < N) {
      int v = cnt[idx];
      rowptr[idx] = run; fill[idx] = run;
      deginv[idx] = 1.0f / (float)(v > 1 ? v : 1);
      run += v;
    }
  }
  if (tid == 255) rowptr[N] = run;
}

__global__ void k_scatter(const int* __restrict__ src, const int* __restrict__ dst,
                          int* __restrict__ fill, int* __restrict__ col) {
  int i = blockIdx.x * 256 + threadIdx.x;
  if (i < E) { int d = dst[i]; int p = atomicAdd(&fill[d], 1); col[p] = src[i]; }
}

__global__ void k_init_params(float* __restrict__ par) {
  int i = threadIdx.x;                 // 64 threads: slot 0 = identity affine
  par[i] = (i < 32) ? 1.0f : 0.0f;
}

// ---------------- enter 1x1 conv: inputs [N,T,3] -> x [n][t][c] ----------------
__global__ void k_enter(const float* __restrict__ in, const float* __restrict__ w,
                        const float* __restrict__ b, float* __restrict__ x) {
  int idx = blockIdx.x * 256 + threadIdx.x;
  if (idx >= N * 13 * 32) return;
  int c = idx & 31; int tmp = idx >> 5; int t = tmp % 13; int n = tmp / 13;
  const float* ip = in + (size_t)n * (13 * 3) + t * 3;
  x[idx] = b[c] + w[c * 3 + 0] * ip[0] + w[c * 3 + 1] * ip[1] + w[c * 3 + 2] * ip[2];
}

// ---------------- gated dilated conv (+ hlast capture) ----------------
template <int TIN, int TOUT, int D>
__global__ __launch_bounds__(256) void k_conv(const float* __restrict__ x,
    const float* __restrict__ fw, const float* __restrict__ fb,
    const float* __restrict__ gw, const float* __restrict__ gb,
    const float* __restrict__ par, int slot, int layer,
    float* __restrict__ h, float* __restrict__ hlast) {
  __shared__ float wf[64 * 33], wg[64 * 33];      // [2i+k][o] padded stride 33
  __shared__ float xs[8][TIN * 32];
  int tx = threadIdx.x, ty = threadIdx.y;
  int tid = ty * 32 + tx;
  const float* fwl = fw + (size_t)layer * 2048;   // [o][i][k] linear = o*64 + 2i + k
  const float* gwl = gw + (size_t)layer * 2048;
  for (int i = tid; i < 2048; i += 256) {
    int o = i >> 6, r = i & 63;
    wf[r * 33 + o] = fwl[i];
    wg[r * 33 + o] = gwl[i];
  }
  int n0 = blockIdx.x * 8;
  const float* scp = par + slot * 64;
  for (int i = tid; i < 8 * TIN * 32; i += 256) {
    int nl = i / (TIN * 32), j = i % (TIN * 32); int c = j & 31;
    int gn = n0 + nl;
    xs[nl][j] = (gn < N) ? (scp[c] * x[(size_t)gn * (TIN * 32) + j] + scp[32 + c]) : 0.0f;
  }
  __syncthreads();
  int o = tx, nn = ty, n = n0 + nn;
  float accF[TOUT], accG[TOUT];
  float fbv = fb[layer * 32 + o], gbv = gb[layer * 32 + o];
#pragma unroll
  for (int t = 0; t < TOUT; t++) { accF[t] = fbv; accG[t] = gbv; }
#pragma unroll
  for (int i = 0; i < 32; i++) {
    float xv[TIN];
#pragma unroll
    for (int t = 0; t < TIN; t++) xv[t] = xs[nn][t * 32 + i];
    float w0 = wf[(2 * i) * 33 + o], w1 = wf[(2 * i + 1) * 33 + o];
    float g0 = wg[(2 * i) * 33 + o], g1 = wg[(2 * i + 1) * 33 + o];
#pragma unroll
    for (int t = 0; t < TOUT; t++) {
      accF[t] += w0 * xv[t] + w1 * xv[t + D];
      accG[t] += g0 * xv[t] + g1 * xv[t + D];
    }
  }
  if (n < N) {
#pragma unroll
    for (int t = 0; t < TOUT; t++) {
      float hv = tanhf(accF[t]) * (1.0f / (1.0f + __expf(-accG[t])));
      h[(size_t)n * (TOUT * 32) + t * 32 + o] = hv;
      if (t == TOUT - 1) hlast[(size_t)n * 256 + layer * 32 + o] = hv;
    }
  }
}

// ---------------- one diffusion hop ----------------
template <int F>
__global__ __launch_bounds__(256) void k_hop(const float* __restrict__ in, float* __restrict__ out,
    const int* __restrict__ rowptr, const int* __restrict__ col, const float* __restrict__ deginv) {
  int wid = (blockIdx.x * 256 + threadIdx.x) >> 6;   // one wave per node
  int lane = threadIdx.x & 63;
  if (wid >= N) return;
  int s = rowptr[wid], e = rowptr[wid + 1];
  constexpr int NCH = (F + 63) / 64;
  float acc[NCH];
#pragma unroll
  for (int k = 0; k < NCH; k++) acc[k] = 0.0f;
  for (int idx = s; idx < e; ++idx) {
    int srcn = col[idx];
    const float* p = in + (size_t)srcn * F;
#pragma unroll
    for (int k = 0; k < NCH; k++) {
      int j = k * 64 + lane;
      if (j < F) acc[k] += p[j];
    }
  }
  float inv = deginv[wid];
  float* q = out + (size_t)wid * F;
#pragma unroll
  for (int k = 0; k < NCH; k++) { int j = k * 64 + lane; if (j < F) q[j] = acc[k] * inv; }
}

// ---------------- combine v2: one thread per (n,t) row ----------------
// acc[o] = sum_k src_k[row] @ W[k] ; out = acc + gcb + psc*xr + psh ; BN stats accumulated.
template <int TOUT>
__global__ __launch_bounds__(256) void k_combine(const float* __restrict__ h,
    const float* __restrict__ c1, const float* __restrict__ c2, const float* __restrict__ c3,
    const float* __restrict__ gcw, const float* __restrict__ gcb,
    const float* __restrict__ xcur, int tin, int layer,
    const float* __restrict__ par, int slot,
    float* __restrict__ xnext, float* __restrict__ sums) {
  __shared__ float ws[4 * 32 * 32];   // [k][c][o]
  __shared__ float pbuf[96];          // gcb[32], psc[32], psh[32]
  __shared__ float r1s[32], r2s[32];
  int tid = threadIdx.x;
  const float* wsrc = gcw + (size_t)layer * 4096;
  for (int i = tid; i < 4096; i += 256) ws[i] = wsrc[i];
  if (tid < 32) {
    pbuf[tid]      = gcb[layer * 32 + tid];
    pbuf[32 + tid] = par[slot * 64 + tid];
    pbuf[64 + tid] = par[slot * 64 + 32 + tid];
    r1s[tid] = 0.0f; r2s[tid] = 0.0f;
  }
  __syncthreads();

  int row = blockIdx.x * 256 + tid;
  bool active = row < N * TOUT;
  int rr = active ? row : 0;
  int n = rr / TOUT;
  int t = rr - n * TOUT;

  float acc[32];
#pragma unroll
  for (int o = 0; o < 32; o++) acc[o] = 0.0f;

  auto do_src = [&](const float* __restrict__ src, int k) {
    const float4* p = (const float4*)(src + (size_t)rr * 32);
    float4 xv[8];
#pragma unroll
    for (int i = 0; i < 8; i++) xv[i] = p[i];
    const float* xvf = (const float*)xv;
#pragma unroll
    for (int c = 0; c < 32; c++) {
      float xc_ = xvf[c];
      const float* wrow = &ws[k * 1024 + c * 32];
#pragma unroll
      for (int o4 = 0; o4 < 8; o4++) {
        float4 w4 = *(const float4*)(wrow + o4 * 4);
        acc[o4 * 4 + 0] += xc_ * w4.x;
        acc[o4 * 4 + 1] += xc_ * w4.y;
        acc[o4 * 4 + 2] += xc_ * w4.z;
        acc[o4 * 4 + 3] += xc_ * w4.w;
      }
    }
  };
  do_src(h, 0);
  do_src(c1, 1);
  do_src(c2, 2);
  do_src(c3, 3);

  // residual + affine; write output
  int toff = tin - TOUT;
  const float4* xrp = (const float4*)(xcur + ((size_t)n * tin + toff + t) * 32);
  float4* outp = (float4*)(xnext + (size_t)rr * 32);
  float vout[32];
#pragma unroll
  for (int i = 0; i < 8; i++) {
    float4 xr = xrp[i];
    float4 v;
    v.x = acc[i * 4 + 0] + pbuf[i * 4 + 0] + pbuf[32 + i * 4 + 0] * xr.x + pbuf[64 + i * 4 + 0];
    v.y = acc[i * 4 + 1] + pbuf[i * 4 + 1] + pbuf[32 + i * 4 + 1] * xr.y + pbuf[64 + i * 4 + 1];
    v.z = acc[i * 4 + 2] + pbuf[i * 4 + 2] + pbuf[32 + i * 4 + 2] * xr.z + pbuf[64 + i * 4 + 2];
    v.w = acc[i * 4 + 3] + pbuf[i * 4 + 3] + pbuf[32 + i * 4 + 3] * xr.w + pbuf[64 + i * 4 + 3];
    vout[i * 4 + 0] = v.x; vout[i * 4 + 1] = v.y; vout[i * 4 + 2] = v.z; vout[i * 4 + 3] = v.w;
    if (active) outp[i] = v;
  }

  // BN stats: per-channel 64-lane butterfly, lane0 -> LDS, block -> global atomics
  int lane = tid & 63;
#pragma unroll
  for (int o = 0; o < 32; o++) {
    float a = active ? vout[o] : 0.0f;
    float b = active ? vout[o] * vout[o] : 0.0f;
#pragma unroll
    for (int off = 32; off > 0; off >>= 1) {
      a += __shfl_xor(a, off);
      b += __shfl_xor(b, off);
    }
    if (lane == 0) { atomicAdd(&r1s[o], a); atomicAdd(&r2s[o], b); }
  }
  __syncthreads();
  if (tid < 32) atomicAdd(&sums[layer * 64 + tid], r1s[tid]);
  else if (tid < 64) atomicAdd(&sums[layer * 64 + tid], r2s[tid - 32]);
}

// ---------------- BN stats -> affine params for next slot ----------------
__global__ void k_bnfin(const float* __restrict__ sums, const float* __restrict__ bng,
                        const float* __restrict__ bnb, float* __restrict__ par,
                        int layer, int tout) {
  int o = threadIdx.x;  // 32
  float cnt = (float)N * (float)tout;
  float s1 = sums[layer * 64 + o], s2 = sums[layer * 64 + 32 + o];
  float mu = s1 / cnt;
  float var = s2 / cnt - mu * mu;
  float sc = bng[layer * 32 + o] * rsqrtf(var + 1e-5f);
  par[(layer + 1) * 64 + o] = sc;
  par[(layer + 1) * 64 + 32 + o] = bnb[layer * 32 + o] - mu * sc;
}

// ---------------- head prep ----------------
__global__ void k_prep_skipw(const float* __restrict__ sw, float* __restrict__ w2) {
  int idx = blockIdx.x * 256 + threadIdx.x;
  if (idx >= 8 * 256 * 32) return;
  int l = idx / (256 * 32), r = idx % (256 * 32), o = r / 32, c = r & 31;
  w2[o * 256 + l * 32 + c] = sw[idx];
}
__global__ void k_prep_sb(const float* __restrict__ sb, float* __restrict__ out) {
  int o = threadIdx.x;  // 256
  float s = 0.0f;
  for (int l = 0; l < 8; l++) s += sb[l * 256 + o];
  out[o] = s;
}

// ---------------- generic tiled fp32 GEMM: C[M,O] = act(A[M,K] @ W[O,K]^T + bias) ----------------
__global__ __launch_bounds__(256) void k_gemm(const float* __restrict__ A, const float* __restrict__ W,
    const float* __restrict__ bias, float* __restrict__ Cout,
    int M, int K, int Onum, int relu) {
  __shared__ float As[16][68];
  __shared__ float Wsh[16][68];
  int tid = threadIdx.x;
  int bm = blockIdx.x * 64, bo = blockIdx.y * 64;
  int tm = (tid >> 4) << 2, to = (tid & 15) << 2;
  float acc[4][4] = {};
  int lm = tid >> 2, kq = (tid & 3) << 2;
  for (int k0 = 0; k0 < K; k0 += 16) {
    float4 av = make_float4(0.f, 0.f, 0.f, 0.f);
    int gm = bm + lm;
    if (gm < M) av = *(const float4*)(A + (size_t)gm * K + k0 + kq);
    As[kq + 0][lm] = av.x; As[kq + 1][lm] = av.y; As[kq + 2][lm] = av.z; As[kq + 3][lm] = av.w;
    float4 wv = *(const float4*)(W + (size_t)(bo + lm) * K + k0 + kq);
    Wsh[kq + 0][lm] = wv.x; Wsh[kq + 1][lm] = wv.y; Wsh[kq + 2][lm] = wv.z; Wsh[kq + 3][lm] = wv.w;
    __syncthreads();
#pragma unroll
    for (int k = 0; k < 16; k++) {
      float am[4], wn[4];
#pragma unroll
      for (int j = 0; j < 4; j++) { am[j] = As[k][tm + j]; wn[j] = Wsh[k][to + j]; }
#pragma unroll
      for (int i = 0; i < 4; i++)
#pragma unroll
        for (int j = 0; j < 4; j++) acc[i][j] += am[i] * wn[j];
    }
    __syncthreads();
  }
#pragma unroll
  for (int i = 0; i < 4; i++) {
    int gm = bm + tm + i; if (gm >= M) continue;
#pragma unroll
    for (int j = 0; j < 4; j++) {
      int go = bo + to + j;
      float v = acc[i][j] + bias[go];
      if (relu) v = fmaxf(v, 0.0f);
      Cout[(size_t)gm * Onum + go] = v;
    }
  }
}

// ---------------- final small GEMM -> d_out [N,24] ----------------
__global__ void k_final(const float* __restrict__ Y1, const float* __restrict__ W2,
                        const float* __restrict__ b2, float* __restrict__ out) {
  int idx = blockIdx.x * 256 + threadIdx.x;
  if (idx >= N * 24) return;
  int n = idx / 24, o = idx % 24;
  const float4* a = (const float4*)(Y1 + (size_t)n * 512);
  const float4* w = (const float4*)(W2 + (size_t)o * 512);
  float s = b2[o];
  for (int k = 0; k < 128; k++) {
    float4 av = a[k], wv = w[k];
    s += av.x * wv.x + av.y * wv.y + av.z * wv.z + av.w * wv.w;
  }
  out[idx] = s;
}

// ---------------- host side ----------------
struct Ptrs {
  const float *fw, *fb, *gw, *gb, *gcw, *gcb, *bng, *bnb;
  float *H, *C1, *C2, *C3, *HL, *par, *sums;
  const int *row, *col;
  const float *deg;
};

template <int TIN, int TOUT, int D>
static void run_layer(int layer, bool last, const Ptrs& P, float*& xc, float*& xn, hipStream_t stream) {
  dim3 cb(32, 8);
  int blocks = (N + 7) / 8;
  k_conv<TIN, TOUT, D><<<blocks, cb, 0, stream>>>(xc, P.fw, P.fb, P.gw, P.gb, P.par, layer, layer, P.H, P.HL);
  if (!last) {
    constexpr int F = TOUT * 32;
    int hb = (N * 64 + 255) / 256;
    k_hop<F><<<hb, 256, 0, stream>>>(P.H, P.C1, P.row, P.col, P.deg);
    k_hop<F><<<hb, 256, 0, stream>>>(P.C1, P.C2, P.row, P.col, P.deg);
    k_hop<F><<<hb, 256, 0, stream>>>(P.C2, P.C3, P.row, P.col, P.deg);
    int cblocks = (N * TOUT + 255) / 256;
    k_combine<TOUT><<<cblocks, 256, 0, stream>>>(P.H, P.C1, P.C2, P.C3, P.gcw, P.gcb, xc, TIN, layer,
                                                 P.par, layer, xn, P.sums);
    k_bnfin<<<1, 32, 0, stream>>>(P.sums, P.bng, P.bnb, P.par, layer, TOUT);
    float* tmp = xc; xc = xn; xn = tmp;
  }
}

extern "C" void kernel_launch(void* const* d_in, const int* in_sizes, int n_in,
                              void* d_out, int out_size, void* d_ws, size_t ws_size,
                              hipStream_t stream) {
  const float* inputs  = (const float*)d_in[0];
  const int*   esrc    = (const int*)d_in[1];
  const int*   edst    = (const int*)d_in[2];
  const float* enter_w = (const float*)d_in[3];
  const float* enter_b = (const float*)d_in[4];
  const float* filt_w  = (const float*)d_in[5];
  const float* filt_b  = (const float*)d_in[6];
  const float* gate_w  = (const float*)d_in[7];
  const float* gate_b  = (const float*)d_in[8];
  const float* gc_w    = (const float*)d_in[9];
  const float* gc_b    = (const float*)d_in[10];
  const float* skip_w  = (const float*)d_in[11];
  const float* skip_b  = (const float*)d_in[12];
  const float* bn_g    = (const float*)d_in[13];
  const float* bn_b    = (const float*)d_in[14];
  const float* out1_w  = (const float*)d_in[15];
  const float* out1_b  = (const float*)d_in[16];
  const float* out2_w  = (const float*)d_in[17];
  const float* out2_b  = (const float*)d_in[18];

  char* ws = (char*)d_ws;
  float* XA  = (float*)(ws + XA_OFF);
  float* XB  = (float*)(ws + XB_OFF);
  float* H   = (float*)(ws + H_OFF);
  float* C1  = (float*)(ws + C1_OFF);
  float* C2  = (float*)(ws + C2_OFF);
  float* C3  = (float*)(ws + C3_OFF);
  float* HL  = (float*)(ws + HL_OFF);
  float* WS2 = (float*)(ws + WS2_OFF);
  float* SB  = (float*)(ws + SB_OFF);
  float* SUMS = (float*)(ws + SUMS_OFF);
  float* PAR  = (float*)(ws + PAR_OFF);
  int* CNT  = (int*)(ws + CNT_OFF);
  int* ROW  = (int*)(ws + ROW_OFF);
  int* FILL = (int*)(ws + FILL_OFF);
  int* COL  = (int*)(ws + COL_OFF);
  float* DEG = (float*)(ws + DEG_OFF);
  float* S  = (float*)(ws + S_OFF);
  float* Y1 = (float*)(ws + Y1_OFF);

  hipMemsetAsync(CNT, 0, (size_t)N * 4, stream);
  hipMemsetAsync(SUMS, 0, 8 * 64 * 4, stream);

  k_count<<<(E + 255) / 256, 256, 0, stream>>>(edst, CNT);
  k_scan<<<1, 256, 0, stream>>>(CNT, ROW, FILL, DEG);
  k_scatter<<<(E + 255) / 256, 256, 0, stream>>>(esrc, edst, FILL, COL);
  k_init_params<<<1, 64, 0, stream>>>(PAR);
  k_enter<<<(N * 13 * 32 + 255) / 256, 256, 0, stream>>>(inputs, enter_w, enter_b, XA);
  k_prep_skipw<<<(8 * 256 * 32 + 255) / 256, 256, 0, stream>>>(skip_w, WS2);
  k_prep_sb<<<1, 256, 0, stream>>>(skip_b, SB);

  Ptrs P;
  P.fw = filt_w; P.fb = filt_b; P.gw = gate_w; P.gb = gate_b;
  P.gcw = gc_w; P.gcb = gc_b; P.bng = bn_g; P.bnb = bn_b;
  P.H = H; P.C1 = C1; P.C2 = C2; P.C3 = C3; P.HL = HL; P.par = PAR; P.sums = SUMS;
  P.row = ROW; P.col = COL; P.deg = DEG;

  float* xc = XA; float* xn = XB;
  run_layer<13, 12, 1>(0, false, P, xc, xn, stream);
  run_layer<12, 10, 2>(1, false, P, xc, xn, stream);
  run_layer<10, 9, 1>(2, false, P, xc, xn, stream);
  run_layer<9, 7, 2>(3, false, P, xc, xn, stream);
  run_layer<7, 6, 1>(4, false, P, xc, xn, stream);
  run_layer<6, 4, 2>(5, false, P, xc, xn, stream);
  run_layer<4, 3, 1>(6, false, P, xc, xn, stream);
  run_layer<3, 1, 2>(7, true, P, xc, xn, stream);

  // head: S = relu(HL @ WS2^T + SB); Y1 = relu(S @ out1_w^T + out1_b); out = Y1 @ out2_w^T + out2_b
  dim3 g1((N + 63) / 64, 256 / 64);
  k_gemm<<<g1, 256, 0, stream>>>(HL, WS2, SB, S, N, 256, 256, 1);
  dim3 g2((N + 63) / 64, 512 / 64);
  k_gemm<<<g2, 256, 0, stream>>>(S, out1_w, out1_b, Y1, N, 256, 512, 1);
  k_final<<<(N * 24 + 255) / 256, 256, 0, stream>>>(Y1, out2_w, out2_b, (float*)d_out);
}

// Round 4
// 4771.410 us; speedup vs baseline: 1.3878x; 1.0153x over previous
//
#include <hip/hip_runtime.h>
#include <cmath>

// ---------------- problem constants ----------------
constexpr int N = 20000, T = 13, E = 320000;

// ---------------- workspace layout ----------------
constexpr size_t WALIGN = 512;
constexpr size_t align_up(size_t x) { return (x + WALIGN - 1) & ~(WALIGN - 1); }

constexpr size_t XA_OFF  = 0;
constexpr size_t X_SZ    = align_up((size_t)N * 13 * 32 * 4);
constexpr size_t XB_OFF  = XA_OFF + X_SZ;
constexpr size_t H_OFF   = XB_OFF + X_SZ;
constexpr size_t H_SZ    = align_up((size_t)N * 12 * 32 * 4);
constexpr size_t C1_OFF  = H_OFF + H_SZ;
constexpr size_t C2_OFF  = C1_OFF + H_SZ;
constexpr size_t C3_OFF  = C2_OFF + H_SZ;
constexpr size_t HL_OFF  = C3_OFF + H_SZ;
constexpr size_t HL_SZ   = align_up((size_t)N * 256 * 4);
constexpr size_t WS2_OFF = HL_OFF + HL_SZ;                 // skip_w transposed 256x256
constexpr size_t SB_OFF  = WS2_OFF + align_up(256 * 256 * 4);
constexpr size_t SUMS_OFF = SB_OFF + align_up(256 * 4);    // 8 layers x 64 floats
constexpr size_t PAR_OFF  = SUMS_OFF + align_up(8 * 64 * 4); // 9 slots x 64 floats
constexpr size_t CNT_OFF  = PAR_OFF + align_up(9 * 64 * 4);
constexpr size_t ROW_OFF  = CNT_OFF + align_up((size_t)N * 4);
constexpr size_t FILL_OFF = ROW_OFF + align_up((size_t)(N + 1) * 4);
constexpr size_t COL_OFF  = FILL_OFF + align_up((size_t)N * 4);
constexpr size_t DEG_OFF  = COL_OFF + align_up((size_t)E * 4);
// aliases used after all layers are done:
constexpr size_t S_OFF  = C2_OFF;   // N*256 floats
constexpr size_t Y1_OFF = H_OFF;    // N*512 floats (spans H+C1)

// ---------------- CSR build ----------------
__global__ void k_count(const int* __restrict__ dst, int* __restrict__ cnt) {
  int i = blockIdx.x * 256 + threadIdx.x;
  if (i < E) atomicAdd(&cnt[dst[i]], 1);
}

__global__ __launch_bounds__(256) void k_scan(const int* __restrict__ cnt, int* __restrict__ rowptr,
                                              int* __restrict__ fill, float* __restrict__ deginv) {
  __shared__ int sc[256];
  int tid = threadIdx.x;
  constexpr int CH = (N + 255) / 256;
  int start = tid * CH;
  int s = 0;
  for (int i = 0; i < CH; i++) { int idx = start + i; if (idx < N) s += cnt[idx]; }
  sc[tid] = s; __syncthreads();
  for (int off = 1; off < 256; off <<= 1) {
    int v = (tid >= off) ? sc[tid - off] : 0;
    __syncthreads();
    sc[tid] += v;
    __syncthreads();
  }
  int run = (tid == 0) ? 0 : sc[tid - 1];
  for (int i = 0; i < CH; i++) {
    int idx = start + i;
    if (idx < N) {
      int v = cnt[idx];
      rowptr[idx] = run; fill[idx] = run;
      deginv[idx] = 1.0f / (float)(v > 1 ? v : 1);
      run += v;
    }
  }
  if (tid == 255) rowptr[N] = run;
}

__global__ void k_scatter(const int* __restrict__ src, const int* __restrict__ dst,
                          int* __restrict__ fill, int* __restrict__ col) {
  int i = blockIdx.x * 256 + threadIdx.x;
  if (i < E) { int d = dst[i]; int p = atomicAdd(&fill[d], 1); col[p] = src[i]; }
}

__global__ void k_init_params(float* __restrict__ par) {
  int i = threadIdx.x;                 // 64 threads: slot 0 = identity affine
  par[i] = (i < 32) ? 1.0f : 0.0f;
}

// ---------------- enter 1x1 conv: inputs [N,T,3] -> x [n][t][c] ----------------
__global__ void k_enter(const float* __restrict__ in, const float* __restrict__ w,
                        const float* __restrict__ b, float* __restrict__ x) {
  int idx = blockIdx.x * 256 + threadIdx.x;
  if (idx >= N * 13 * 32) return;
  int c = idx & 31; int tmp = idx >> 5; int t = tmp % 13; int n = tmp / 13;
  const float* ip = in + (size_t)n * (13 * 3) + t * 3;
  x[idx] = b[c] + w[c * 3 + 0] * ip[0] + w[c * 3 + 1] * ip[1] + w[c * 3 + 2] * ip[2];
}

// ---------------- gated dilated conv (+ hlast capture) ----------------
template <int TIN, int TOUT, int D>
__global__ __launch_bounds__(256) void k_conv(const float* __restrict__ x,
    const float* __restrict__ fw, const float* __restrict__ fb,
    const float* __restrict__ gw, const float* __restrict__ gb,
    const float* __restrict__ par, int slot, int layer,
    float* __restrict__ h, float* __restrict__ hlast) {
  __shared__ float wf[64 * 33], wg[64 * 33];      // [2i+k][o] padded stride 33
  __shared__ float xs[8][TIN * 32];
  int tx = threadIdx.x, ty = threadIdx.y;
  int tid = ty * 32 + tx;
  const float* fwl = fw + (size_t)layer * 2048;   // [o][i][k] linear = o*64 + 2i + k
  const float* gwl = gw + (size_t)layer * 2048;
  for (int i = tid; i < 2048; i += 256) {
    int o = i >> 6, r = i & 63;
    wf[r * 33 + o] = fwl[i];
    wg[r * 33 + o] = gwl[i];
  }
  int n0 = blockIdx.x * 8;
  const float* scp = par + slot * 64;
  for (int i = tid; i < 8 * TIN * 32; i += 256) {
    int nl = i / (TIN * 32), j = i % (TIN * 32); int c = j & 31;
    int gn = n0 + nl;
    xs[nl][j] = (gn < N) ? (scp[c] * x[(size_t)gn * (TIN * 32) + j] + scp[32 + c]) : 0.0f;
  }
  __syncthreads();
  int o = tx, nn = ty, n = n0 + nn;
  float accF[TOUT], accG[TOUT];
  float fbv = fb[layer * 32 + o], gbv = gb[layer * 32 + o];
#pragma unroll
  for (int t = 0; t < TOUT; t++) { accF[t] = fbv; accG[t] = gbv; }
#pragma unroll
  for (int i = 0; i < 32; i++) {
    float xv[TIN];
#pragma unroll
    for (int t = 0; t < TIN; t++) xv[t] = xs[nn][t * 32 + i];
    float w0 = wf[(2 * i) * 33 + o], w1 = wf[(2 * i + 1) * 33 + o];
    float g0 = wg[(2 * i) * 33 + o], g1 = wg[(2 * i + 1) * 33 + o];
#pragma unroll
    for (int t = 0; t < TOUT; t++) {
      accF[t] += w0 * xv[t] + w1 * xv[t + D];
      accG[t] += g0 * xv[t] + g1 * xv[t + D];
    }
  }
  if (n < N) {
#pragma unroll
    for (int t = 0; t < TOUT; t++) {
      float hv = tanhf(accF[t]) * (1.0f / (1.0f + __expf(-accG[t])));
      h[(size_t)n * (TOUT * 32) + t * 32 + o] = hv;
      if (t == TOUT - 1) hlast[(size_t)n * 256 + layer * 32 + o] = hv;
    }
  }
}

// ---------------- one diffusion hop ----------------
template <int F>
__global__ __launch_bounds__(256) void k_hop(const float* __restrict__ in, float* __restrict__ out,
    const int* __restrict__ rowptr, const int* __restrict__ col, const float* __restrict__ deginv) {
  int wid = (blockIdx.x * 256 + threadIdx.x) >> 6;   // one wave per node
  int lane = threadIdx.x & 63;
  if (wid >= N) return;
  int s = rowptr[wid], e = rowptr[wid + 1];
  constexpr int NCH = (F + 63) / 64;
  float acc[NCH];
#pragma unroll
  for (int k = 0; k < NCH; k++) acc[k] = 0.0f;
  for (int idx = s; idx < e; ++idx) {
    int srcn = col[idx];
    const float* p = in + (size_t)srcn * F;
#pragma unroll
    for (int k = 0; k < NCH; k++) {
      int j = k * 64 + lane;
      if (j < F) acc[k] += p[j];
    }
  }
  float inv = deginv[wid];
  float* q = out + (size_t)wid * F;
#pragma unroll
  for (int k = 0; k < NCH; k++) { int j = k * 64 + lane; if (j < F) q[j] = acc[k] * inv; }
}

// ---------------- combine v3: one thread per (n,t) row; LDS-staged coalesced output ----------------
template <int TOUT>
__global__ __launch_bounds__(256) void k_combine(const float* __restrict__ h,
    const float* __restrict__ c1, const float* __restrict__ c2, const float* __restrict__ c3,
    const float* __restrict__ gcw, const float* __restrict__ gcb,
    const float* __restrict__ xcur, int tin, int layer,
    const float* __restrict__ par, int slot,
    float* __restrict__ xnext, float* __restrict__ sums) {
  __shared__ float ws[4 * 32 * 32];   // [k][c][o]
  __shared__ float obuf[256 * 33];    // padded output staging
  __shared__ float pbuf[96];          // gcb[32], psc[32], psh[32]
  __shared__ float r1s[32], r2s[32];
  int tid = threadIdx.x;
  const float* wsrc = gcw + (size_t)layer * 4096;
  for (int i = tid; i < 4096; i += 256) ws[i] = wsrc[i];
  if (tid < 32) {
    pbuf[tid]      = gcb[layer * 32 + tid];
    pbuf[32 + tid] = par[slot * 64 + tid];
    pbuf[64 + tid] = par[slot * 64 + 32 + tid];
    r1s[tid] = 0.0f; r2s[tid] = 0.0f;
  }
  __syncthreads();

  int row = blockIdx.x * 256 + tid;
  bool active = row < N * TOUT;
  int rr = active ? row : 0;
  int n = rr / TOUT;
  int t = rr - n * TOUT;

  float acc[32];
#pragma unroll
  for (int o = 0; o < 32; o++) acc[o] = 0.0f;

  auto do_src = [&](const float* __restrict__ src, int k) {
    const float4* p = (const float4*)(src + (size_t)rr * 32);
    float4 xv[8];
#pragma unroll
    for (int i = 0; i < 8; i++) xv[i] = p[i];
    const float* xvf = (const float*)xv;
#pragma unroll
    for (int c = 0; c < 32; c++) {
      float xc_ = xvf[c];
      const float* wrow = &ws[k * 1024 + c * 32];
#pragma unroll
      for (int o4 = 0; o4 < 8; o4++) {
        float4 w4 = *(const float4*)(wrow + o4 * 4);
        acc[o4 * 4 + 0] += xc_ * w4.x;
        acc[o4 * 4 + 1] += xc_ * w4.y;
        acc[o4 * 4 + 2] += xc_ * w4.z;
        acc[o4 * 4 + 3] += xc_ * w4.w;
      }
    }
  };
  do_src(h, 0);
  do_src(c1, 1);
  do_src(c2, 2);
  do_src(c3, 3);

  // residual + affine; stash to LDS (padded row stride 33 -> <=2-way bank aliasing)
  int toff = tin - TOUT;
  const float4* xrp = (const float4*)(xcur + ((size_t)n * tin + toff + t) * 32);
  float vout[32];
#pragma unroll
  for (int i = 0; i < 8; i++) {
    float4 xr = xrp[i];
    vout[i * 4 + 0] = acc[i * 4 + 0] + pbuf[i * 4 + 0] + pbuf[32 + i * 4 + 0] * xr.x + pbuf[64 + i * 4 + 0];
    vout[i * 4 + 1] = acc[i * 4 + 1] + pbuf[i * 4 + 1] + pbuf[32 + i * 4 + 1] * xr.y + pbuf[64 + i * 4 + 1];
    vout[i * 4 + 2] = acc[i * 4 + 2] + pbuf[i * 4 + 2] + pbuf[32 + i * 4 + 2] * xr.z + pbuf[64 + i * 4 + 2];
    vout[i * 4 + 3] = acc[i * 4 + 3] + pbuf[i * 4 + 3] + pbuf[32 + i * 4 + 3] * xr.w + pbuf[64 + i * 4 + 3];
  }
#pragma unroll
  for (int c = 0; c < 32; c++) obuf[tid * 33 + c] = vout[c];

  // BN stats: per-channel 64-lane butterfly, lane0 -> LDS, block -> global atomics
  int lane = tid & 63;
#pragma unroll
  for (int o = 0; o < 32; o++) {
    float a = active ? vout[o] : 0.0f;
    float b = active ? vout[o] * vout[o] : 0.0f;
#pragma unroll
    for (int off = 32; off > 0; off >>= 1) {
      a += __shfl_xor(a, off);
      b += __shfl_xor(b, off);
    }
    if (lane == 0) { atomicAdd(&r1s[o], a); atomicAdd(&r2s[o], b); }
  }
  __syncthreads();

  // cooperative coalesced store: block's output span is contiguous 256 rows x 32 floats
  int total4 = N * TOUT * 8;                       // float4 count in xnext
  float4* outp = (float4*)xnext;
  int base4 = blockIdx.x * 2048;
#pragma unroll
  for (int j = 0; j < 8; j++) {
    int l = j * 256 + tid;                         // local float4 index
    int g = base4 + l;
    if (g < total4) {
      int rloc = l >> 3, c4 = l & 7;
      const float* src = &obuf[rloc * 33 + c4 * 4];
      float4 v = make_float4(src[0], src[1], src[2], src[3]);
      outp[g] = v;
    }
  }

  if (tid < 32) atomicAdd(&sums[layer * 64 + tid], r1s[tid]);
  else if (tid < 64) atomicAdd(&sums[layer * 64 + tid], r2s[tid - 32]);
}

// ---------------- BN stats -> affine params for next slot ----------------
__global__ void k_bnfin(const float* __restrict__ sums, const float* __restrict__ bng,
                        const float* __restrict__ bnb, float* __restrict__ par,
                        int layer, int tout) {
  int o = threadIdx.x;  // 32
  float cnt = (float)N * (float)tout;
  float s1 = sums[layer * 64 + o], s2 = sums[layer * 64 + 32 + o];
  float mu = s1 / cnt;
  float var = s2 / cnt - mu * mu;
  float sc = bng[layer * 32 + o] * rsqrtf(var + 1e-5f);
  par[(layer + 1) * 64 + o] = sc;
  par[(layer + 1) * 64 + 32 + o] = bnb[layer * 32 + o] - mu * sc;
}

// ---------------- head prep ----------------
__global__ void k_prep_skipw(const float* __restrict__ sw, float* __restrict__ w2) {
  int idx = blockIdx.x * 256 + threadIdx.x;
  if (idx >= 8 * 256 * 32) return;
  int l = idx / (256 * 32), r = idx % (256 * 32), o = r / 32, c = r & 31;
  w2[o * 256 + l * 32 + c] = sw[idx];
}
__global__ void k_prep_sb(const float* __restrict__ sb, float* __restrict__ out) {
  int o = threadIdx.x;  // 256
  float s = 0.0f;
  for (int l = 0; l < 8; l++) s += sb[l * 256 + o];
  out[o] = s;
}

// ---------------- generic tiled fp32 GEMM: C[M,O] = act(A[M,K] @ W[O,K]^T + bias) ----------------
__global__ __launch_bounds__(256) void k_gemm(const float* __restrict__ A, const float* __restrict__ W,
    const float* __restrict__ bias, float* __restrict__ Cout,
    int M, int K, int Onum, int relu) {
  __shared__ float As[16][68];
  __shared__ float Wsh[16][68];
  int tid = threadIdx.x;
  int bm = blockIdx.x * 64, bo = blockIdx.y * 64;
  int tm = (tid >> 4) << 2, to = (tid & 15) << 2;
  float acc[4][4] = {};
  int lm = tid >> 2, kq = (tid & 3) << 2;
  for (int k0 = 0; k0 < K; k0 += 16) {
    float4 av = make_float4(0.f, 0.f, 0.f, 0.f);
    int gm = bm + lm;
    if (gm < M) av = *(const float4*)(A + (size_t)gm * K + k0 + kq);
    As[kq + 0][lm] = av.x; As[kq + 1][lm] = av.y; As[kq + 2][lm] = av.z; As[kq + 3][lm] = av.w;
    float4 wv = *(const float4*)(W + (size_t)(bo + lm) * K + k0 + kq);
    Wsh[kq + 0][lm] = wv.x; Wsh[kq + 1][lm] = wv.y; Wsh[kq + 2][lm] = wv.z; Wsh[kq + 3][lm] = wv.w;
    __syncthreads();
#pragma unroll
    for (int k = 0; k < 16; k++) {
      float am[4], wn[4];
#pragma unroll
      for (int j = 0; j < 4; j++) { am[j] = As[k][tm + j]; wn[j] = Wsh[k][to + j]; }
#pragma unroll
      for (int i = 0; i < 4; i++)
#pragma unroll
        for (int j = 0; j < 4; j++) acc[i][j] += am[i] * wn[j];
    }
    __syncthreads();
  }
#pragma unroll
  for (int i = 0; i < 4; i++) {
    int gm = bm + tm + i; if (gm >= M) continue;
#pragma unroll
    for (int j = 0; j < 4; j++) {
      int go = bo + to + j;
      float v = acc[i][j] + bias[go];
      if (relu) v = fmaxf(v, 0.0f);
      Cout[(size_t)gm * Onum + go] = v;
    }
  }
}

// ---------------- final small GEMM -> d_out [N,24] ----------------
__global__ void k_final(const float* __restrict__ Y1, const float* __restrict__ W2,
                        const float* __restrict__ b2, float* __restrict__ out) {
  int idx = blockIdx.x * 256 + threadIdx.x;
  if (idx >= N * 24) return;
  int n = idx / 24, o = idx % 24;
  const float4* a = (const float4*)(Y1 + (size_t)n * 512);
  const float4* w = (const float4*)(W2 + (size_t)o * 512);
  float s = b2[o];
  for (int k = 0; k < 128; k++) {
    float4 av = a[k], wv = w[k];
    s += av.x * wv.x + av.y * wv.y + av.z * wv.z + av.w * wv.w;
  }
  out[idx] = s;
}

// ---------------- host side ----------------
struct Ptrs {
  const float *fw, *fb, *gw, *gb, *gcw, *gcb, *bng, *bnb;
  float *H, *C1, *C2, *C3, *HL, *par, *sums;
  const int *row, *col;
  const float *deg;
};

template <int TIN, int TOUT, int D>
static void run_layer(int layer, bool last, const Ptrs& P, float*& xc, float*& xn, hipStream_t stream) {
  dim3 cb(32, 8);
  int blocks = (N + 7) / 8;
  k_conv<TIN, TOUT, D><<<blocks, cb, 0, stream>>>(xc, P.fw, P.fb, P.gw, P.gb, P.par, layer, layer, P.H, P.HL);
  if (!last) {
    constexpr int F = TOUT * 32;
    int hb = (N * 64 + 255) / 256;
    k_hop<F><<<hb, 256, 0, stream>>>(P.H, P.C1, P.row, P.col, P.deg);
    k_hop<F><<<hb, 256, 0, stream>>>(P.C1, P.C2, P.row, P.col, P.deg);
    k_hop<F><<<hb, 256, 0, stream>>>(P.C2, P.C3, P.row, P.col, P.deg);
    int cblocks = (N * TOUT + 255) / 256;
    k_combine<TOUT><<<cblocks, 256, 0, stream>>>(P.H, P.C1, P.C2, P.C3, P.gcw, P.gcb, xc, TIN, layer,
                                                 P.par, layer, xn, P.sums);
    k_bnfin<<<1, 32, 0, stream>>>(P.sums, P.bng, P.bnb, P.par, layer, TOUT);
    float* tmp = xc; xc = xn; xn = tmp;
  }
}

extern "C" void kernel_launch(void* const* d_in, const int* in_sizes, int n_in,
                              void* d_out, int out_size, void* d_ws, size_t ws_size,
                              hipStream_t stream) {
  const float* inputs  = (const float*)d_in[0];
  const int*   esrc    = (const int*)d_in[1];
  const int*   edst    = (const int*)d_in[2];
  const float* enter_w = (const float*)d_in[3];
  const float* enter_b = (const float*)d_in[4];
  const float* filt_w  = (const float*)d_in[5];
  const float* filt_b  = (const float*)d_in[6];
  const float* gate_w  = (const float*)d_in[7];
  const float* gate_b  = (const float*)d_in[8];
  const float* gc_w    = (const float*)d_in[9];
  const float* gc_b    = (const float*)d_in[10];
  const float* skip_w  = (const float*)d_in[11];
  const float* skip_b  = (const float*)d_in[12];
  const float* bn_g    = (const float*)d_in[13];
  const float* bn_b    = (const float*)d_in[14];
  const float* out1_w  = (const float*)d_in[15];
  const float* out1_b  = (const float*)d_in[16];
  const float* out2_w  = (const float*)d_in[17];
  const float* out2_b  = (const float*)d_in[18];

  char* ws = (char*)d_ws;
  float* XA  = (float*)(ws + XA_OFF);
  float* XB  = (float*)(ws + XB_OFF);
  float* H   = (float*)(ws + H_OFF);
  float* C1  = (float*)(ws + C1_OFF);
  float* C2  = (float*)(ws + C2_OFF);
  float* C3  = (float*)(ws + C3_OFF);
  float* HL  = (float*)(ws + HL_OFF);
  float* WS2 = (float*)(ws + WS2_OFF);
  float* SB  = (float*)(ws + SB_OFF);
  float* SUMS = (float*)(ws + SUMS_OFF);
  float* PAR  = (float*)(ws + PAR_OFF);
  int* CNT  = (int*)(ws + CNT_OFF);
  int* ROW  = (int*)(ws + ROW_OFF);
  int* FILL = (int*)(ws + FILL_OFF);
  int* COL  = (int*)(ws + COL_OFF);
  float* DEG = (float*)(ws + DEG_OFF);
  float* S  = (float*)(ws + S_OFF);
  float* Y1 = (float*)(ws + Y1_OFF);

  hipMemsetAsync(CNT, 0, (size_t)N * 4, stream);
  hipMemsetAsync(SUMS, 0, 8 * 64 * 4, stream);

  k_count<<<(E + 255) / 256, 256, 0, stream>>>(edst, CNT);
  k_scan<<<1, 256, 0, stream>>>(CNT, ROW, FILL, DEG);
  k_scatter<<<(E + 255) / 256, 256, 0, stream>>>(esrc, edst, FILL, COL);
  k_init_params<<<1, 64, 0, stream>>>(PAR);
  k_enter<<<(N * 13 * 32 + 255) / 256, 256, 0, stream>>>(inputs, enter_w, enter_b, XA);
  k_prep_skipw<<<(8 * 256 * 32 + 255) / 256, 256, 0, stream>>>(skip_w, WS2);
  k_prep_sb<<<1, 256, 0, stream>>>(skip_b, SB);

  Ptrs P;
  P.fw = filt_w; P.fb = filt_b; P.gw = gate_w; P.gb = gate_b;
  P.gcw = gc_w; P.gcb = gc_b; P.bng = bn_g; P.bnb = bn_b;
  P.H = H; P.C1 = C1; P.C2 = C2; P.C3 = C3; P.HL = HL; P.par = PAR; P.sums = SUMS;
  P.row = ROW; P.col = COL; P.deg = DEG;

  float* xc = XA; float* xn = XB;
  run_layer<13, 12, 1>(0, false, P, xc, xn, stream);
  run_layer<12, 10, 2>(1, false, P, xc, xn, stream);
  run_layer<10, 9, 1>(2, false, P, xc, xn, stream);
  run_layer<9, 7, 2>(3, false, P, xc, xn, stream);
  run_layer<7, 6, 1>(4, false, P, xc, xn, stream);
  run_layer<6, 4, 2>(5, false, P, xc, xn, stream);
  run_layer<4, 3, 1>(6, false, P, xc, xn, stream);
  run_layer<3, 1, 2>(7, true, P, xc, xn, stream);

  // head: S = relu(HL @ WS2^T + SB); Y1 = relu(S @ out1_w^T + out1_b); out = Y1 @ out2_w^T + out2_b
  dim3 g1((N + 63) / 64, 256 / 64);
  k_gemm<<<g1, 256, 0, stream>>>(HL, WS2, SB, S, N, 256, 256, 1);
  dim3 g2((N + 63) / 64, 512 / 64);
  k_gemm<<<g2, 256, 0, stream>>>(S, out1_w, out1_b, Y1, N, 256, 512, 1);
  k_final<<<(N * 24 + 255) / 256, 256, 0, stream>>>(Y1, out2_w, out2_b, (float*)d_out);
}